// Round 5
// baseline (13.597 us; speedup 1.0000x reference)
//
#include <hip/hip_runtime.h>

#define NUM_CLASS 121
#define BROWS 262144
#define THREADS 256
#define ROWS_PER_THREAD 2
#define BLOCKS (BROWS / (THREADS * ROWS_PER_THREAD))   // 512
#define RBLOCKS 1024                                   // partial count (see below)
#define TOTAL (BROWS * NUM_CLASS)                      // 31719424 < 2^31

// Kernel 1: two consecutive rows per thread.
// Labels for the pair come from one coalesced int2 load; then all four
// float4 window loads are issued before any log/FMA so the wave has 4
// independent gather requests in flight on top of the shared label latency.
// The 5 taps of row r always lie in the aligned 8-float window at
// ga = clamp((r*121 + lab - 2) & ~3, 0, TOTAL-8).
__global__ __launch_bounds__(THREADS)
void sce_partial(const float* __restrict__ pred,
                 const int*   __restrict__ label,
                 const float* __restrict__ kw,
                 float*       __restrict__ partial) {
    const int t = blockIdx.x * THREADS + threadIdx.x;   // pair index

    const float w0 = kw[0], w1 = kw[1], w2 = kw[2], w3 = kw[3], w4 = kw[4];

    const int2 L = reinterpret_cast<const int2*>(label)[t];

    const int r0   = 2 * t;
    const int b0   = r0 * NUM_CLASS;
    const int b1   = b0 + NUM_CLASS;
    const int g0   = b0 + L.x - 2;
    const int g1   = b1 + L.y - 2;

    int ga0 = g0 & ~3;  ga0 = ga0 < 0 ? 0 : (ga0 > TOTAL - 8 ? TOTAL - 8 : ga0);
    int ga1 = g1 & ~3;  ga1 = ga1 < 0 ? 0 : (ga1 > TOTAL - 8 ? TOTAL - 8 : ga1);

    // issue all four gathers before consuming anything
    const float4 a0 = *reinterpret_cast<const float4*>(pred + ga0);
    const float4 a1 = *reinterpret_cast<const float4*>(pred + ga0 + 4);
    const float4 c0 = *reinterpret_cast<const float4*>(pred + ga1);
    const float4 c1 = *reinterpret_cast<const float4*>(pred + ga1 + 4);

    const float va[8] = {a0.x, a0.y, a0.z, a0.w, a1.x, a1.y, a1.z, a1.w};
    const float vb[8] = {c0.x, c0.y, c0.z, c0.w, c1.x, c1.y, c1.z, c1.w};

    float acc = 0.0f;
    #pragma unroll
    for (int i = 0; i < 8; ++i) {
        // row 0 of the pair
        {
            const int j = (ga0 - g0) + i;          // tap index, valid 0..4
            const int c = (ga0 - b0) + i;          // class index
            const bool ok = (j >= 0) & (j < 5) & (c >= 0) & (c < NUM_CLASS);
            float wj = (j <= 0) ? w0 : (j == 1) ? w1 : (j == 2) ? w2
                     : (j == 3) ? w3 : w4;
            wj = ok ? wj : 0.0f;
            acc -= wj * __logf(va[i] + 1e-8f);
        }
        // row 1 of the pair
        {
            const int j = (ga1 - g1) + i;
            const int c = (ga1 - b1) + i;
            const bool ok = (j >= 0) & (j < 5) & (c >= 0) & (c < NUM_CLASS);
            float wj = (j <= 0) ? w0 : (j == 1) ? w1 : (j == 2) ? w2
                     : (j == 3) ? w3 : w4;
            wj = ok ? wj : 0.0f;
            acc -= wj * __logf(vb[i] + 1e-8f);
        }
    }

    // wave-64 butterfly reduce
    #pragma unroll
    for (int off = 32; off > 0; off >>= 1)
        acc += __shfl_down(acc, off, 64);

    __shared__ float wsum[THREADS / 64];
    const int lane = threadIdx.x & 63;
    const int wid  = threadIdx.x >> 6;
    if (lane == 0) wsum[wid] = acc;
    __syncthreads();

    if (threadIdx.x == 0)
        partial[blockIdx.x] = wsum[0] + wsum[1] + wsum[2] + wsum[3];
}

// Kernel 2: single block reduces the partials, scales, stores the scalar.
__global__ __launch_bounds__(THREADS)
void sce_reduce(const float* __restrict__ partial,
                float*       __restrict__ out) {
    float acc = 0.0f;
    #pragma unroll
    for (int i = threadIdx.x; i < BLOCKS; i += THREADS)
        acc += partial[i];

    #pragma unroll
    for (int off = 32; off > 0; off >>= 1)
        acc += __shfl_down(acc, off, 64);

    __shared__ float wsum[THREADS / 64];
    const int lane = threadIdx.x & 63;
    const int wid  = threadIdx.x >> 6;
    if (lane == 0) wsum[wid] = acc;
    __syncthreads();

    if (threadIdx.x == 0) {
        const float s = wsum[0] + wsum[1] + wsum[2] + wsum[3];
        out[0] = s * (1.0f / ((float)BROWS * (float)NUM_CLASS));
    }
}

extern "C" void kernel_launch(void* const* d_in, const int* in_sizes, int n_in,
                              void* d_out, int out_size, void* d_ws, size_t ws_size,
                              hipStream_t stream) {
    const float* pred  = (const float*)d_in[0];
    const int*   label = (const int*)d_in[1];
    const float* kw    = (const float*)d_in[2];
    float*       out   = (float*)d_out;
    float*       part  = (float*)d_ws;       // 512 floats = 2 KiB scratch

    sce_partial<<<BLOCKS, THREADS, 0, stream>>>(pred, label, kw, part);
    sce_reduce<<<1, THREADS, 0, stream>>>(part, out);
}

// Round 6
// 13.098 us; speedup vs baseline: 1.0381x; 1.0381x over previous
//
#include <hip/hip_runtime.h>

#define NUM_CLASS 121
#define BROWS 262144
#define THREADS 256
#define THREADS_PER_ROW 2
#define NTHREADS (BROWS * THREADS_PER_ROW)      // 524288
#define BLOCKS (NTHREADS / THREADS)             // 2048 -> 8192 waves = 32/CU (max occ)
#define TOTAL (BROWS * NUM_CLASS)               // 31719424 < 2^31

// Kernel 1: TWO threads per row (half = tid&1). The 5 taps of row r lie in the
// aligned 8-float window at ga = clamp((r*121+lab-2)&~3, 0, TOTAL-8); the even
// lane loads floats [ga, ga+4), the odd lane [ga+4, ga+8) — adjacent addresses
// merge in the coalescer. Max-occupancy grid (32 waves/CU) to hide the
// two-round-trip label->gather dependent chain.
__global__ __launch_bounds__(THREADS)
void sce_partial(const float* __restrict__ pred,
                 const int*   __restrict__ label,
                 const float* __restrict__ kw,
                 float*       __restrict__ partial) {
    const int tid  = blockIdx.x * THREADS + threadIdx.x;
    const int row  = tid >> 1;
    const int half = tid & 1;

    const float w0 = kw[0], w1 = kw[1], w2 = kw[2], w3 = kw[3], w4 = kw[4];

    const int lab  = label[row];                // pair of lanes broadcast-share
    const int base = row * NUM_CLASS;
    const int g    = base + lab - 2;            // flat index of tap j=0
    int ga = g & ~3;                            // 16B-aligned window start
    ga = ga < 0 ? 0 : ga;
    ga = ga > (TOTAL - 8) ? (TOTAL - 8) : ga;

    const float4 q = *reinterpret_cast<const float4*>(pred + ga + 4 * half);
    const float v[4] = {q.x, q.y, q.z, q.w};

    float acc = 0.0f;
    #pragma unroll
    for (int i = 0; i < 4; ++i) {
        const int slot = 4 * half + i;          // window slot 0..7
        const int j = (ga - g) + slot;          // tap index; valid taps 0..4
        const int c = (ga - base) + slot;       // class index of this slot
        const bool ok = (j >= 0) & (j < 5) & (c >= 0) & (c < NUM_CLASS);
        float wj = (j <= 0) ? w0 : (j == 1) ? w1 : (j == 2) ? w2
                 : (j == 3) ? w3 : w4;
        wj = ok ? wj : 0.0f;
        acc -= wj * __logf(v[i] + 1e-8f);       // v_log_f32 (validated R3/R4)
    }

    // wave-64 butterfly reduce
    #pragma unroll
    for (int off = 32; off > 0; off >>= 1)
        acc += __shfl_down(acc, off, 64);

    __shared__ float wsum[THREADS / 64];
    const int lane = threadIdx.x & 63;
    const int wid  = threadIdx.x >> 6;
    if (lane == 0) wsum[wid] = acc;
    __syncthreads();

    if (threadIdx.x == 0)
        partial[blockIdx.x] = wsum[0] + wsum[1] + wsum[2] + wsum[3];
}

// Kernel 2: single block reduces BLOCKS partials (vectorized), stores scalar.
__global__ __launch_bounds__(THREADS)
void sce_reduce(const float* __restrict__ partial,
                float*       __restrict__ out) {
    const float4* p4 = reinterpret_cast<const float4*>(partial);
    float acc = 0.0f;
    #pragma unroll
    for (int i = threadIdx.x; i < BLOCKS / 4; i += THREADS) {
        const float4 q = p4[i];
        acc += (q.x + q.y) + (q.z + q.w);
    }

    #pragma unroll
    for (int off = 32; off > 0; off >>= 1)
        acc += __shfl_down(acc, off, 64);

    __shared__ float wsum[THREADS / 64];
    const int lane = threadIdx.x & 63;
    const int wid  = threadIdx.x >> 6;
    if (lane == 0) wsum[wid] = acc;
    __syncthreads();

    if (threadIdx.x == 0) {
        const float s = wsum[0] + wsum[1] + wsum[2] + wsum[3];
        out[0] = s * (1.0f / ((float)BROWS * (float)NUM_CLASS));
    }
}

extern "C" void kernel_launch(void* const* d_in, const int* in_sizes, int n_in,
                              void* d_out, int out_size, void* d_ws, size_t ws_size,
                              hipStream_t stream) {
    const float* pred  = (const float*)d_in[0];
    const int*   label = (const int*)d_in[1];
    const float* kw    = (const float*)d_in[2];
    float*       out   = (float*)d_out;
    float*       part  = (float*)d_ws;       // 2048 floats = 8 KiB scratch

    sce_partial<<<BLOCKS, THREADS, 0, stream>>>(pred, label, kw, part);
    sce_reduce<<<1, THREADS, 0, stream>>>(part, out);
}

// Round 7
// 12.407 us; speedup vs baseline: 1.0959x; 1.0557x over previous
//
#include <hip/hip_runtime.h>

#define NUM_CLASS 121
#define BROWS 262144
#define THREADS 256
#define BLOCKS (BROWS / THREADS)          // 1024
#define TOTAL (BROWS * NUM_CLASS)          // 31719424 < 2^31

// Kernel 1 (R4-exact best config): one thread per row.
// The 5 taps pred[row, lab-2..lab+2] (clipped) always lie in the 8-float
// aligned window at ga = clamp((row*121+lab-2)&~3, 0, TOTAL-8). Two float4
// loads per row, predicated weights per window slot, __logf (validated).
__global__ __launch_bounds__(THREADS)
void sce_partial(const float* __restrict__ pred,
                 const int*   __restrict__ label,
                 const float* __restrict__ kw,
                 float*       __restrict__ partial) {
    const int row = blockIdx.x * THREADS + threadIdx.x;   // grid covers BROWS exactly

    const float w0 = kw[0], w1 = kw[1], w2 = kw[2], w3 = kw[3], w4 = kw[4];

    const int lab  = label[row];
    const int base = row * NUM_CLASS;
    const int g    = base + lab - 2;       // flat index of tap j=0
    int ga = g & ~3;                       // 16B-aligned window start
    ga = ga < 0 ? 0 : ga;
    ga = ga > (TOTAL - 8) ? (TOTAL - 8) : ga;

    const float4 q0 = *reinterpret_cast<const float4*>(pred + ga);
    const float4 q1 = *reinterpret_cast<const float4*>(pred + ga + 4);
    const float v[8] = {q0.x, q0.y, q0.z, q0.w, q1.x, q1.y, q1.z, q1.w};

    float acc = 0.0f;
    #pragma unroll
    for (int i = 0; i < 8; ++i) {
        const int j = (ga - g) + i;        // tap index; valid taps are 0..4
        const int c = (ga - base) + i;     // class index of this window slot
        const bool ok = (j >= 0) & (j < 5) & (c >= 0) & (c < NUM_CLASS);
        float wj = (j <= 0) ? w0 : (j == 1) ? w1 : (j == 2) ? w2
                 : (j == 3) ? w3 : w4;
        wj = ok ? wj : 0.0f;
        acc -= wj * __logf(v[i] + 1e-8f);
    }

    #pragma unroll
    for (int off = 32; off > 0; off >>= 1)
        acc += __shfl_down(acc, off, 64);

    __shared__ float wsum[THREADS / 64];
    const int lane = threadIdx.x & 63;
    const int wid  = threadIdx.x >> 6;
    if (lane == 0) wsum[wid] = acc;
    __syncthreads();

    if (threadIdx.x == 0)
        partial[blockIdx.x] = wsum[0] + wsum[1] + wsum[2] + wsum[3];
}

// Kernel 2: single block, 256 threads, ONE float4 per thread covers all
// 1024 partials in a single VMEM instruction -> one memory round-trip,
// then shuffle+LDS reduce and the scaled scalar store.
__global__ __launch_bounds__(THREADS)
void sce_reduce(const float* __restrict__ partial,
                float*       __restrict__ out) {
    const float4 q = reinterpret_cast<const float4*>(partial)[threadIdx.x];
    float acc = (q.x + q.y) + (q.z + q.w);

    #pragma unroll
    for (int off = 32; off > 0; off >>= 1)
        acc += __shfl_down(acc, off, 64);

    __shared__ float wsum[THREADS / 64];
    const int lane = threadIdx.x & 63;
    const int wid  = threadIdx.x >> 6;
    if (lane == 0) wsum[wid] = acc;
    __syncthreads();

    if (threadIdx.x == 0) {
        const float s = wsum[0] + wsum[1] + wsum[2] + wsum[3];
        out[0] = s * (1.0f / ((float)BROWS * (float)NUM_CLASS));
    }
}

extern "C" void kernel_launch(void* const* d_in, const int* in_sizes, int n_in,
                              void* d_out, int out_size, void* d_ws, size_t ws_size,
                              hipStream_t stream) {
    const float* pred  = (const float*)d_in[0];
    const int*   label = (const int*)d_in[1];
    const float* kw    = (const float*)d_in[2];
    float*       out   = (float*)d_out;
    float*       part  = (float*)d_ws;       // 1024 floats = 4 KiB scratch

    sce_partial<<<BLOCKS, THREADS, 0, stream>>>(pred, label, kw, part);
    sce_reduce<<<1, THREADS, 0, stream>>>(part, out);
}